// Round 19
// baseline (549.065 us; speedup 1.0000x reference)
//
#include <hip/hip_runtime.h>

#define TT 2048
#define DD 1024
#define ND3 3072
#define LL 4
#define MAXIT 12
#define NBLK 256
#define NRG 32   // max row-groups (32 rows each)

typedef float f32x4 __attribute__((ext_vector_type(4)));
typedef __bf16 bf16x8 __attribute__((ext_vector_type(8)));
typedef unsigned long long ull_t;

__device__ __forceinline__ float sigmoidf_(float x) { return 1.f / (1.f + __expf(-x)); }

__device__ __forceinline__ float gru_out(float xr, float xz, float xn,
                                         float hr, float hz, float hn, float hp)
{
    float rg = sigmoidf_(xr + hr);
    float zg = sigmoidf_(xz + hz);
    float ng = tanhf(xn + rg * hn);
    return (1.f - zg) * ng + zg * hp;
}

__device__ __forceinline__ ushort f2bf(float x)
{
    unsigned u = __builtin_bit_cast(unsigned, x);
    return (ushort)((u + 0x7FFFu + ((u >> 16) & 1u)) >> 16);
}

__device__ __forceinline__ float bf2f(ushort u)
{
    return __builtin_bit_cast(float, ((unsigned)u) << 16);
}

__device__ __forceinline__ void gld_lds16(const void* g, void* l)
{
    __builtin_amdgcn_global_load_lds(
        (const __attribute__((address_space(1))) unsigned int*)g,
        (__attribute__((address_space(3))) unsigned int*)l, 16, 0, 0);
}

// ---------------------------------------------------------------------------
// Episode segmentation + counting sort (verbatim round 8).
// ---------------------------------------------------------------------------
__global__ __launch_bounds__(256)
void seg_kernel(const int* __restrict__ term, int* __restrict__ g_start,
                int* __restrict__ g_len, int* __restrict__ g_perm,
                int* __restrict__ g_nact)
{
    __shared__ int s_start[TT + 1];
    __shared__ int s_len[TT];
    __shared__ int s_hist[TT + 1];
    __shared__ int s_base[TT + 1];
    __shared__ int s_p[256];
    __shared__ int s_wsum[33];
    __shared__ int s_n;
    int tid = threadIdx.x, lane = tid & 63, wv = tid >> 6;

    for (int i = tid; i <= TT; i += 256) s_hist[i] = 0;

    unsigned long long msk[8];
#pragma unroll
    for (int p = 0; p < 8; ++p) {
        int t = p * 256 + tid;
        int bit = (t == 0) || (term[t] != 0);
        unsigned long long m = __ballot(bit);
        msk[p] = m;
        if (lane == 0) s_wsum[p * 4 + wv] = __popcll(m);
    }
    __syncthreads();
    if (tid == 0) {
        int run = 0;
        for (int i = 0; i < 32; ++i) { int v = s_wsum[i]; s_wsum[i] = run; run += v; }
        s_n = run;
    }
    __syncthreads();
    int n = s_n;
#pragma unroll
    for (int p = 0; p < 8; ++p) {
        int t = p * 256 + tid;
        unsigned long long m = msk[p];
        if ((m >> lane) & 1ull) {
            int e = s_wsum[p * 4 + wv] + __popcll(m & ((1ull << lane) - 1ull));
            s_start[e] = t;
        }
    }
    if (tid == 0) s_start[n] = TT;
    __syncthreads();
    for (int e = tid; e < n; e += 256) {
        int L = s_start[e + 1] - s_start[e];
        s_len[e] = L;
        atomicAdd(&s_hist[L], 1);
    }
    __syncthreads();
    int lo = 8 * tid + 1;
    int p_i = 0;
#pragma unroll
    for (int j = 0; j < 8; ++j) p_i += s_hist[lo + j];
    s_p[tid] = p_i;
    __syncthreads();
    if (tid < 64) {
        int q0 = s_p[tid * 4], q1 = s_p[tid * 4 + 1], q2 = s_p[tid * 4 + 2], q3 = s_p[tid * 4 + 3];
        int q = q0 + q1 + q2 + q3;
        int acc = q;
        for (int off = 1; off < 64; off <<= 1) {
            int v = __shfl_down(acc, off);
            if (lane + off < 64) acc += v;
        }
        int ex = acc - q;
        s_p[tid * 4 + 3] = ex;
        s_p[tid * 4 + 2] = ex + q3;
        s_p[tid * 4 + 1] = ex + q3 + q2;
        s_p[tid * 4 + 0] = ex + q3 + q2 + q1;
    }
    __syncthreads();
    int running = s_p[tid];
    for (int j = 7; j >= 0; --j) {
        s_base[lo + j] = running;
        running += s_hist[lo + j];
    }
    __syncthreads();
    if (tid == 0) g_nact[0] = n;
    if (tid >= 1 && tid <= MAXIT) g_nact[tid] = s_base[tid];
    __syncthreads();
    for (int e = tid; e < n; e += 256) {
        g_start[e] = s_start[e];
        int L = s_len[e];
        g_len[e] = L;
        int pos = atomicAdd(&s_base[L], 1);
        g_perm[pos] = e;
    }
}

// ---------------------------------------------------------------------------
__global__ __launch_bounds__(256)
void cast_bf(const float* __restrict__ src, ushort* __restrict__ dst, int n)
{
    int base = (blockIdx.x * 256 + threadIdx.x) * 4;
    if (base < n) {
        float4 v = *(const float4*)(src + base);
        ushort4 o;
        o.x = f2bf(v.x); o.y = f2bf(v.y); o.z = f2bf(v.z); o.w = f2bf(v.w);
        *(ushort4*)(dst + base) = o;
    }
}

// ---------------------------------------------------------------------------
// Transpose + cast ALL weight matrices (float4 reads, verbatim round 16).
// ---------------------------------------------------------------------------
__global__ __launch_bounds__(256)
void transcast_all(const float* __restrict__ Wi, const float* __restrict__ Wh,
                   ushort* __restrict__ WT_all, ushort* __restrict__ WhT_all)
{
    int z = blockIdx.z;
    int l = z >> 1;
    const float* src = ((z & 1) ? Wh : Wi) + (size_t)l * DD * ND3;
    ushort* dst = ((z & 1) ? WhT_all : WT_all) + (size_t)l * ND3 * DD;
    __shared__ float tile[64][65];
    int tid = threadIdx.x;
    int n0 = blockIdx.x * 64, k0 = blockIdx.y * 64;
#pragma unroll
    for (int i = 0; i < 4; ++i) {
        int idx = i * 256 + tid;
        int r = idx >> 4, c4 = idx & 15;
        float4 v = *(const float4*)&src[(size_t)(k0 + r) * ND3 + n0 + c4 * 4];
        tile[r][c4 * 4 + 0] = v.x;
        tile[r][c4 * 4 + 1] = v.y;
        tile[r][c4 * 4 + 2] = v.z;
        tile[r][c4 * 4 + 3] = v.w;
    }
    __syncthreads();
#pragma unroll
    for (int i = 0; i < 4; ++i) {
        int idx = i * 256 + tid;
        int nr = idx >> 4, kq = idx & 15;
        float a0 = tile[kq * 4 + 0][nr];
        float a1 = tile[kq * 4 + 1][nr];
        float a2 = tile[kq * 4 + 2][nr];
        float a3 = tile[kq * 4 + 3][nr];
        ushort4 o;
        o.x = f2bf(a0); o.y = f2bf(a1); o.z = f2bf(a2); o.w = f2bf(a3);
        *(ushort4*)&dst[(size_t)(n0 + nr) * DD + k0 + kq * 4] = o;
    }
}

// ---------------------------------------------------------------------------
// Phase A GEMM (verbatim round 8, verified).
// ---------------------------------------------------------------------------
__global__ __launch_bounds__(256)
void gemm_mfma(const ushort* __restrict__ A, const ushort* __restrict__ BT,
               ushort* __restrict__ C)
{
    __shared__ __align__(16) ushort As[128 * 32];
    __shared__ __align__(16) ushort Bs[128 * 32];
    int tid = threadIdx.x, lane = tid & 63, wv = tid >> 6;
    int m0 = blockIdx.y * 128, n0 = blockIdx.x * 128;
    int wr = wv >> 1, wc = wv & 1;
    f32x4 acc[4][4] = {};

    int ci0 = tid, ci1 = 256 + tid;
    int r0s = ci0 >> 2, r1s = ci1 >> 2;
    int ss0 = (ci0 & 3) ^ ((r0s >> 1) & 3);
    int ss1 = (ci1 & 3) ^ ((r1s >> 1) & 3);
    const ushort* Ar0 = A + (size_t)(m0 + r0s) * DD + ss0 * 8;
    const ushort* Ar1 = A + (size_t)(m0 + r1s) * DD + ss1 * 8;
    const ushort* Br0 = BT + (size_t)(n0 + r0s) * DD + ss0 * 8;
    const ushort* Br1 = BT + (size_t)(n0 + r1s) * DD + ss1 * 8;

    int g = lane >> 4, fr = lane & 15;

    for (int k0 = 0; k0 < DD; k0 += 32) {
        gld_lds16(Ar0 + k0, (char*)As + wv * 1024);
        gld_lds16(Ar1 + k0, (char*)As + 4096 + wv * 1024);
        gld_lds16(Br0 + k0, (char*)Bs + wv * 1024);
        gld_lds16(Br1 + k0, (char*)Bs + 4096 + wv * 1024);
        __syncthreads();

        bf16x8 af[4], bb[4];
#pragma unroll
        for (int mi = 0; mi < 4; ++mi) {
            int row = wr * 64 + mi * 16 + fr;
            int slot = g ^ ((row >> 1) & 3);
            af[mi] = *(const bf16x8*)(As + row * 32 + slot * 8);
        }
#pragma unroll
        for (int ni = 0; ni < 4; ++ni) {
            int row = wc * 64 + ni * 16 + fr;
            int slot = g ^ ((row >> 1) & 3);
            bb[ni] = *(const bf16x8*)(Bs + row * 32 + slot * 8);
        }
#pragma unroll
        for (int mi = 0; mi < 4; ++mi)
#pragma unroll
            for (int ni = 0; ni < 4; ++ni)
                acc[mi][ni] = __builtin_amdgcn_mfma_f32_16x16x32_bf16(
                    af[mi], bb[ni], acc[mi][ni], 0, 0, 0);
        __syncthreads();
    }

    int orow = (lane >> 4) * 4, ocol = lane & 15;
#pragma unroll
    for (int mi = 0; mi < 4; ++mi)
#pragma unroll
        for (int ni = 0; ni < 4; ++ni)
#pragma unroll
            for (int r2 = 0; r2 < 4; ++r2)
                C[(size_t)(m0 + wr * 64 + mi * 16 + orow + r2) * ND3 +
                  n0 + wc * 64 + ni * 16 + ocol] = f2bf(acc[mi][ni][r2]);
}

// ---------------------------------------------------------------------------
// Iteration 0 (verbatim round 8).
// ---------------------------------------------------------------------------
__global__ __launch_bounds__(256)
void it0_kernel(const ushort* __restrict__ xp, const float* __restrict__ Wh,
                const float* __restrict__ bh, const float* __restrict__ h0g,
                const int* __restrict__ term, float* __restrict__ Hnext,
                ushort* __restrict__ Hbfn, ushort* __restrict__ ybf,
                float* __restrict__ yf32, float* __restrict__ finals,
                const int* __restrict__ g_start, const int* __restrict__ g_perm,
                const int* __restrict__ g_nact)
{
    int M = g_nact[0];
    int r = blockIdx.x;
    if (r >= M) return;
    int e = g_perm[r];
    int t = g_start[e];
    int tid = threadIdx.x;
    bool useh0 = (t == 0) && (term[0] == 0);
    __shared__ float h0s[DD];
    __shared__ int s_nz;
    if (tid == 0) s_nz = 0;
    __syncthreads();
    if (useh0) {
        int nz = 0;
#pragma unroll
        for (int j = 0; j < 4; ++j) {
            float v = h0g[tid + j * 256];
            h0s[tid + j * 256] = v;
            nz |= (v != 0.f) ? 1 : 0;
        }
        if (nz) atomicOr(&s_nz, 1);
    }
    __syncthreads();
    bool gemv = useh0 && (s_nz != 0);
#pragma unroll
    for (int j = 0; j < 4; ++j) {
        int c = tid + j * 256;
        float hr = bh[c], hz = bh[DD + c], hn = bh[2 * DD + c];
        if (gemv) {
            for (int k = 0; k < DD; ++k) {
                float hv = h0s[k];
                hr += hv * Wh[(size_t)k * ND3 + c];
                hz += hv * Wh[(size_t)k * ND3 + DD + c];
                hn += hv * Wh[(size_t)k * ND3 + 2 * DD + c];
            }
        }
        float hp = useh0 ? h0s[c] : 0.f;
        float xr = bf2f(xp[(size_t)t * ND3 + c]);
        float xz = bf2f(xp[(size_t)t * ND3 + DD + c]);
        float xn = bf2f(xp[(size_t)t * ND3 + 2 * DD + c]);
        float hnew = gru_out(xr, xz, xn, hr, hz, hn, hp);
        Hnext[(size_t)e * DD + c] = hnew;
        Hbfn[(size_t)e * DD + c] = f2bf(hnew);
        if (yf32) yf32[(size_t)t * DD + c] = hnew;
        else      ybf[(size_t)t * DD + c] = f2bf(hnew);
        if (t == TT - 1) finals[c] = hnew;
    }
}

// ---------------------------------------------------------------------------
// Phase B fused. Round-18 wide-tile layout with the LDS-base BUG FIXED:
// every global_load_lds destination now includes the per-wave offset
// (wv*1024) — gld_lds writes wave-uniform-base + lane*16, so the base must
// be distinct per wave. Chunk c = p*256 + wv*64 + lane lands at byte c*16,
// restoring the verified self-cancelling slot swizzle.
// 256 thr / 4 waves; wave owns 32 rows x 16 hcols x 3 gates; 12 MFMA and
// 10 LDS fragment reads per k-step (block LDS traffic 40KB/step vs 64).
// ---------------------------------------------------------------------------
__global__ __launch_bounds__(256)
void phaseb_kernel(float* __restrict__ Hb0, float* __restrict__ Hb1,
                   ushort* __restrict__ Hbf0, ushort* __restrict__ Hbf1,
                   const ushort* __restrict__ xp, const ushort* __restrict__ WhT,
                   const float* __restrict__ bh, ushort* __restrict__ ybf,
                   float* __restrict__ yf32, float* __restrict__ finals,
                   const int* __restrict__ g_start, const int* __restrict__ g_perm,
                   const int* __restrict__ g_nact, unsigned* __restrict__ flags)
{
    __shared__ __align__(16) ushort As[3 * 32 * 64];     // 3 x 4 KB
    __shared__ __align__(16) ushort Bs[3 * 192 * 64];    // 3 x 24 KB
    __shared__ int s_e[32], s_t[32], s_v[32];
    int tid = threadIdx.x, lane = tid & 63, wv = tid >> 6;   // wv 0..3
    int fr = lane & 15, g = lane >> 4;
    int hw = wv * 16;
    int wb = wv * 1024;                 // per-wave LDS base offset (the fix)
    int cs = blockIdx.x & 15, bw = blockIdx.x >> 4;
    int c0 = cs * 64;
    int col = c0 + hw + fr;
    float bhv0 = bh[col], bhv1 = bh[DD + col], bhv2 = bh[2 * DD + col];

    // B staging sources (pre-swizzled global): 6 passes x 256 chunks of 16B.
    const ushort* srcB[6];
#pragma unroll
    for (int p = 0; p < 6; ++p) {
        int c = p * 256 + tid;
        int j = c >> 3;                 // B row 0..191
        int f = j >> 6;
        int coln = c0 + (j & 63);
        int sl = (c & 7) ^ (j & 7);
        srcB[p] = WhT + (size_t)(f * DD + coln) * DD + sl * 8;
    }

    // A-strip geometry: row = tid>>3 (0..31), j8 = tid&7; per step this
    // thread owns 16B = logical slot j8, phys slot j8^(row&7).
    int arowi = tid >> 3;
    int j8 = tid & 7;
    int dstb = arowi * 128 + (j8 ^ (arowi & 7)) * 16;

    for (int it = 1; it < MAXIT; ++it) {
        int M = g_nact[it];   // uniform, read-only
        if (bw * 32 >= M) break;   // monotone: never active again
        float*  Hp   = (it & 1) ? Hb0 : Hb1;
        float*  Hn   = (it & 1) ? Hb1 : Hb0;
        ushort* Hbfp = (it & 1) ? Hbf0 : Hbf1;
        ushort* Hbfn = (it & 1) ? Hbf1 : Hbf0;

        for (int rg = bw; rg * 32 < M; rg += 16) {
            int r0 = rg * 32;

            __syncthreads();   // LDS reuse guard (prev tile fully read)
            if (tid < 32) {
                int r = r0 + tid;
                int v = (r < M) ? 1 : 0;
                int e = v ? g_perm[r] : 0;
                s_e[tid] = e;
                s_v[tid] = v;
                s_t[tid] = v ? (g_start[e] + it) : 0;
            }
            __syncthreads();   // publish s_e/s_t/s_v

            // --- flag-independent prefetch (runs while we wait) ---
#pragma unroll
            for (int p = 0; p < 6; ++p)
                gld_lds16(srcB[p], (char*)Bs + p * 4096 + wb);
#pragma unroll
            for (int p = 0; p < 6; ++p)
                gld_lds16(srcB[p] + 64, (char*)Bs + 24576 + p * 4096 + wb);
            float xrv[2][4], xzv[2][4], xnv[2][4];
#pragma unroll
            for (int rf = 0; rf < 2; ++rf)
#pragma unroll
                for (int r2 = 0; r2 < 4; ++r2) {
                    int row = rf * 16 + g * 4 + r2;
                    size_t tb = (size_t)s_t[row] * ND3;
                    xrv[rf][r2] = bf2f(xp[tb + col]);
                    xzv[rf][r2] = bf2f(xp[tb + DD + col]);
                    xnv[rf][r2] = bf2f(xp[tb + 2 * DD + col]);
                }

            // --- wait for the 16 it-1 producers (parallel per-slot poll) ---
            if (it > 1 && tid < 16) {
                const unsigned* slot =
                    flags + ((size_t)(it - 1) * NRG + rg) * 256 + tid * 16;
                while (__hip_atomic_load(slot, __ATOMIC_RELAXED,
                                         __HIP_MEMORY_SCOPE_AGENT) == 0u)
                    __builtin_amdgcn_s_sleep(1);
            }
            __syncthreads();

            // --- flag-dependent: A-strip + Hp (LLC-coherent) ---
            int rr = r0 + arowi; if (rr > M - 1) rr = M - 1;
            int eA = g_perm[rr];
            const ull_t* srcA8 = (const ull_t*)(Hbfp + (size_t)eA * DD);
            ull_t a0[16], a1[16];
#pragma unroll
            for (int kk = 0; kk < 16; ++kk) {
                int c = kk * 16 + j8 * 2;
                a0[kk] = __hip_atomic_load(srcA8 + c, __ATOMIC_RELAXED,
                                           __HIP_MEMORY_SCOPE_AGENT);
                a1[kk] = __hip_atomic_load(srcA8 + c + 1, __ATOMIC_RELAXED,
                                           __HIP_MEMORY_SCOPE_AGENT);
            }
            float hpv[2][4];
#pragma unroll
            for (int rf = 0; rf < 2; ++rf)
#pragma unroll
                for (int r2 = 0; r2 < 4; ++r2) {
                    int row = rf * 16 + g * 4 + r2;
                    hpv[rf][r2] = __hip_atomic_load(
                        Hp + (size_t)s_e[row] * DD + col,
                        __ATOMIC_RELAXED, __HIP_MEMORY_SCOPE_AGENT);
                }
            asm volatile("s_waitcnt vmcnt(0)" ::: "memory");
            *(ull_t*)((char*)As + dstb) = a0[0];
            *(ull_t*)((char*)As + dstb + 8) = a1[0];
            *(ull_t*)((char*)As + 4096 + dstb) = a0[1];
            *(ull_t*)((char*)As + 4096 + dstb + 8) = a1[1];

            f32x4 acc[2][3] = {};
#pragma unroll
            for (int kk = 0; kk < 16; ++kk) {
                if (kk == 15)
                    asm volatile("s_waitcnt vmcnt(0) lgkmcnt(0)" ::: "memory");
                else
                    asm volatile("s_waitcnt vmcnt(6) lgkmcnt(0)" ::: "memory");
                __builtin_amdgcn_s_barrier();
                if (kk < 14) {
                    const int nb = (kk + 2) % 3;
                    char* bdst = (char*)Bs + nb * 24576 + wb;
#pragma unroll
                    for (int p = 0; p < 6; ++p)
                        gld_lds16(srcB[p] + (kk + 2) * 64, bdst + p * 4096);
                    *(ull_t*)((char*)As + nb * 4096 + dstb) = a0[kk + 2];
                    *(ull_t*)((char*)As + nb * 4096 + dstb + 8) = a1[kk + 2];
                }
                const int cb = kk % 3;
                const ushort* Acur = As + cb * 2048;
                const ushort* Bcur = Bs + cb * 12288;
#pragma unroll
                for (int kw = 0; kw < 2; ++kw) {
                    int sl = kw * 4 + g;
                    bf16x8 af0, af1;
                    {
                        int ar = fr;           // rf=0 row
                        af0 = *(const bf16x8*)(Acur + ar * 64 + (sl ^ (ar & 7)) * 8);
                        int ar1 = 16 + fr;     // rf=1 row
                        af1 = *(const bf16x8*)(Acur + ar1 * 64 + (sl ^ (ar1 & 7)) * 8);
                    }
#pragma unroll
                    for (int f = 0; f < 3; ++f) {
                        int jf = f * 64 + hw + fr;
                        bf16x8 bbv = *(const bf16x8*)(Bcur + jf * 64 + (sl ^ (jf & 7)) * 8);
                        acc[0][f] = __builtin_amdgcn_mfma_f32_16x16x32_bf16(af0, bbv, acc[0][f], 0, 0, 0);
                        acc[1][f] = __builtin_amdgcn_mfma_f32_16x16x32_bf16(af1, bbv, acc[1][f], 0, 0, 0);
                    }
                }
            }

#pragma unroll
            for (int rf = 0; rf < 2; ++rf)
#pragma unroll
                for (int r2 = 0; r2 < 4; ++r2) {
                    int row = rf * 16 + g * 4 + r2;
                    if (!s_v[row]) continue;   // uniform across the fr^1 pair
                    int e = s_e[row], t = s_t[row];
                    float hr = acc[rf][0][r2] + bhv0;
                    float hz = acc[rf][1][r2] + bhv1;
                    float hn = acc[rf][2][r2] + bhv2;
                    float hnew = gru_out(xrv[rf][r2], xzv[rf][r2], xnv[rf][r2],
                                         hr, hz, hn, hpv[rf][r2]);
                    __hip_atomic_store(Hn + (size_t)e * DD + col, hnew,
                                       __ATOMIC_RELAXED, __HIP_MEMORY_SCOPE_AGENT);
                    ushort mybf = f2bf(hnew);
                    unsigned other = __shfl_xor((unsigned)mybf, 1);
                    if ((fr & 1) == 0)
                        __hip_atomic_store((unsigned*)(Hbfn + (size_t)e * DD + col),
                                           (unsigned)mybf | (other << 16),
                                           __ATOMIC_RELAXED, __HIP_MEMORY_SCOPE_AGENT);
                    if (yf32) yf32[(size_t)t * DD + col] = hnew;
                    else      ybf[(size_t)t * DD + col] = mybf;
                    if (t == TT - 1) finals[col] = hnew;
                }

            __syncthreads();   // drain epilogue stores (vmcnt(0)) before flag
            if (tid == 0)
                __hip_atomic_store(
                    flags + ((size_t)it * NRG + rg) * 256 + cs * 16, 1u,
                    __ATOMIC_RELAXED, __HIP_MEMORY_SCOPE_AGENT);
        }
    }
}

// ---------------------------------------------------------------------------
// Cleanup (verbatim round 8; no-op when no episode exceeds MAXIT).
// ---------------------------------------------------------------------------
__global__ __launch_bounds__(256)
void cleanup_kernel(const float* __restrict__ Hlast, const ushort* __restrict__ xp,
                    const float* __restrict__ Wh, const float* __restrict__ bh,
                    ushort* __restrict__ ybf, float* __restrict__ yf32,
                    float* __restrict__ finals, const int* __restrict__ g_start,
                    const int* __restrict__ g_len, const int* __restrict__ g_perm,
                    const int* __restrict__ g_nact)
{
    int Mt = g_nact[MAXIT];
    if (Mt == 0) return;
    __shared__ float h[DD];
    int tid = threadIdx.x;
    for (int r = blockIdx.x; r < Mt; r += gridDim.x) {
        int e = g_perm[r];
        int s0 = g_start[e];
        int L = g_len[e];
#pragma unroll
        for (int j = 0; j < 4; ++j) h[tid + j * 256] = Hlast[(size_t)e * DD + tid + j * 256];
        __syncthreads();
        for (int i = MAXIT; i < L; ++i) {
            int t = s0 + i;
            float hnew[4];
#pragma unroll
            for (int j = 0; j < 4; ++j) {
                int c = tid + j * 256;
                float hr = bh[c], hz = bh[DD + c], hn = bh[2 * DD + c];
                for (int k = 0; k < DD; ++k) {
                    float hv = h[k];
                    hr += hv * Wh[(size_t)k * ND3 + c];
                    hz += hv * Wh[(size_t)k * ND3 + DD + c];
                    hn += hv * Wh[(size_t)k * ND3 + 2 * DD + c];
                }
                float xr = bf2f(xp[(size_t)t * ND3 + c]);
                float xz = bf2f(xp[(size_t)t * ND3 + DD + c]);
                float xn = bf2f(xp[(size_t)t * ND3 + 2 * DD + c]);
                float hp = h[c];
                hnew[j] = gru_out(xr, xz, xn, hr, hz, hn, hp);
                if (yf32) yf32[(size_t)t * DD + c] = hnew[j];
                else      ybf[(size_t)t * DD + c] = f2bf(hnew[j]);
                if (t == TT - 1) finals[c] = hnew[j];
            }
            __syncthreads();
#pragma unroll
            for (int j = 0; j < 4; ++j) h[tid + j * 256] = hnew[j];
            __syncthreads();
        }
        __syncthreads();
    }
}

// ---------------------------------------------------------------------------
extern "C" void kernel_launch(void* const* d_in, const int* in_sizes, int n_in,
                              void* d_out, int out_size, void* d_ws, size_t ws_size,
                              hipStream_t stream)
{
    const float* x_in = (const float*)d_in[0];
    const int*   term = (const int*)d_in[1];
    const float* h0   = (const float*)d_in[2];
    const float* Wi   = (const float*)d_in[3];
    const float* Wh   = (const float*)d_in[4];
    const float* bh   = (const float*)d_in[5];
    float* out = (float*)d_out;

    ushort* xp      = (ushort*)d_ws;                      // TT*ND3 bf16
    float*  Hb0     = (float*)(xp + (size_t)TT * ND3);    // TT*DD fp32
    float*  Hb1     = Hb0 + (size_t)TT * DD;              // TT*DD fp32
    ushort* Hbf0    = (ushort*)(Hb1 + (size_t)TT * DD);   // TT*DD bf16
    ushort* Hbf1    = Hbf0 + (size_t)TT * DD;             // TT*DD bf16
    ushort* Xbf     = Hbf1 + (size_t)TT * DD;             // TT*DD bf16
    ushort* Yb0     = Xbf + (size_t)TT * DD;              // TT*DD bf16
    ushort* Yb1     = Yb0 + (size_t)TT * DD;              // TT*DD bf16
    ushort* WT_all  = Yb1 + (size_t)TT * DD;              // LL*ND3*DD bf16
    ushort* WhT_all = WT_all + (size_t)LL * ND3 * DD;     // LL*ND3*DD bf16
    int* ib      = (int*)(WhT_all + (size_t)LL * ND3 * DD);
    int* g_start = ib;                 // TT
    int* g_len   = ib + TT;            // TT
    int* g_perm  = ib + 2 * TT;        // TT
    int* g_nact  = ib + 3 * TT;        // 64
    unsigned* flagws = (unsigned*)(ib + 3 * TT + 64);   // LL*MAXIT*NRG*16*16 uints

    hipMemsetAsync(flagws, 0,
                   (size_t)LL * MAXIT * NRG * 16 * 16 * sizeof(unsigned), stream);
    seg_kernel<<<1, 256, 0, stream>>>(term, g_start, g_len, g_perm, g_nact);
    cast_bf<<<(TT * DD / 4 + 255) / 256, 256, 0, stream>>>(x_in, Xbf, TT * DD);
    transcast_all<<<dim3(ND3 / 64, DD / 64, 2 * LL), 256, 0, stream>>>(
        Wi, Wh, WT_all, WhT_all);

    const ushort* Abf[4] = { Xbf, Yb0, Yb1, Yb0 };
    ushort*       Ybo[4] = { Yb0, Yb1, Yb0, nullptr };

    for (int l = 0; l < LL; ++l) {
        const float* Whl = Wh + (size_t)l * DD * ND3;
        const float* bhl = bh + (size_t)l * ND3;
        const ushort* WTl  = WT_all + (size_t)l * ND3 * DD;
        const ushort* WhTl = WhT_all + (size_t)l * ND3 * DD;
        float* yf32 = (l == LL - 1) ? out : nullptr;
        ushort* ybf = Ybo[l];
        float* finals = out + (size_t)TT * DD + (size_t)l * DD;

        gemm_mfma<<<dim3(ND3 / 128, TT / 128), 256, 0, stream>>>(Abf[l], WTl, xp);

        it0_kernel<<<TT, 256, 0, stream>>>(xp, Whl, bhl, h0 + (size_t)l * DD, term,
                                           Hb0, Hbf0, ybf, yf32, finals,
                                           g_start, g_perm, g_nact);

        phaseb_kernel<<<NBLK, 256, 0, stream>>>(
            Hb0, Hb1, Hbf0, Hbf1, xp, WhTl, bhl, ybf, yf32, finals,
            g_start, g_perm, g_nact,
            flagws + (size_t)l * MAXIT * NRG * 256);

        float* Hlast = ((MAXIT - 1) & 1) ? Hb1 : Hb0;
        cleanup_kernel<<<64, 256, 0, stream>>>(Hlast, xp, Whl, bhl, ybf, yf32,
                                               finals, g_start, g_len, g_perm,
                                               g_nact);
    }
}

// Round 20
// 472.232 us; speedup vs baseline: 1.1627x; 1.1627x over previous
//
#include <hip/hip_runtime.h>

#define TT 2048
#define DD 1024
#define ND3 3072
#define LL 4
#define MAXIT 12
#define NBLK 256
#define NRG 32   // max row-groups (32 rows each)

typedef float f32x4 __attribute__((ext_vector_type(4)));
typedef __bf16 bf16x8 __attribute__((ext_vector_type(8)));
typedef unsigned long long ull_t;

__device__ __forceinline__ float sigmoidf_(float x) { return 1.f / (1.f + __expf(-x)); }

__device__ __forceinline__ float gru_out(float xr, float xz, float xn,
                                         float hr, float hz, float hn, float hp)
{
    float rg = sigmoidf_(xr + hr);
    float zg = sigmoidf_(xz + hz);
    float ng = tanhf(xn + rg * hn);
    return (1.f - zg) * ng + zg * hp;
}

__device__ __forceinline__ ushort f2bf(float x)
{
    unsigned u = __builtin_bit_cast(unsigned, x);
    return (ushort)((u + 0x7FFFu + ((u >> 16) & 1u)) >> 16);
}

__device__ __forceinline__ float bf2f(ushort u)
{
    return __builtin_bit_cast(float, ((unsigned)u) << 16);
}

__device__ __forceinline__ void gld_lds16(const void* g, void* l)
{
    __builtin_amdgcn_global_load_lds(
        (const __attribute__((address_space(1))) unsigned int*)g,
        (__attribute__((address_space(3))) unsigned int*)l, 16, 0, 0);
}

// ---------------------------------------------------------------------------
// Episode segmentation + counting sort (verbatim round 8).
// ---------------------------------------------------------------------------
__global__ __launch_bounds__(256)
void seg_kernel(const int* __restrict__ term, int* __restrict__ g_start,
                int* __restrict__ g_len, int* __restrict__ g_perm,
                int* __restrict__ g_nact)
{
    __shared__ int s_start[TT + 1];
    __shared__ int s_len[TT];
    __shared__ int s_hist[TT + 1];
    __shared__ int s_base[TT + 1];
    __shared__ int s_p[256];
    __shared__ int s_wsum[33];
    __shared__ int s_n;
    int tid = threadIdx.x, lane = tid & 63, wv = tid >> 6;

    for (int i = tid; i <= TT; i += 256) s_hist[i] = 0;

    unsigned long long msk[8];
#pragma unroll
    for (int p = 0; p < 8; ++p) {
        int t = p * 256 + tid;
        int bit = (t == 0) || (term[t] != 0);
        unsigned long long m = __ballot(bit);
        msk[p] = m;
        if (lane == 0) s_wsum[p * 4 + wv] = __popcll(m);
    }
    __syncthreads();
    if (tid == 0) {
        int run = 0;
        for (int i = 0; i < 32; ++i) { int v = s_wsum[i]; s_wsum[i] = run; run += v; }
        s_n = run;
    }
    __syncthreads();
    int n = s_n;
#pragma unroll
    for (int p = 0; p < 8; ++p) {
        int t = p * 256 + tid;
        unsigned long long m = msk[p];
        if ((m >> lane) & 1ull) {
            int e = s_wsum[p * 4 + wv] + __popcll(m & ((1ull << lane) - 1ull));
            s_start[e] = t;
        }
    }
    if (tid == 0) s_start[n] = TT;
    __syncthreads();
    for (int e = tid; e < n; e += 256) {
        int L = s_start[e + 1] - s_start[e];
        s_len[e] = L;
        atomicAdd(&s_hist[L], 1);
    }
    __syncthreads();
    int lo = 8 * tid + 1;
    int p_i = 0;
#pragma unroll
    for (int j = 0; j < 8; ++j) p_i += s_hist[lo + j];
    s_p[tid] = p_i;
    __syncthreads();
    if (tid < 64) {
        int q0 = s_p[tid * 4], q1 = s_p[tid * 4 + 1], q2 = s_p[tid * 4 + 2], q3 = s_p[tid * 4 + 3];
        int q = q0 + q1 + q2 + q3;
        int acc = q;
        for (int off = 1; off < 64; off <<= 1) {
            int v = __shfl_down(acc, off);
            if (lane + off < 64) acc += v;
        }
        int ex = acc - q;
        s_p[tid * 4 + 3] = ex;
        s_p[tid * 4 + 2] = ex + q3;
        s_p[tid * 4 + 1] = ex + q3 + q2;
        s_p[tid * 4 + 0] = ex + q3 + q2 + q1;
    }
    __syncthreads();
    int running = s_p[tid];
    for (int j = 7; j >= 0; --j) {
        s_base[lo + j] = running;
        running += s_hist[lo + j];
    }
    __syncthreads();
    if (tid == 0) g_nact[0] = n;
    if (tid >= 1 && tid <= MAXIT) g_nact[tid] = s_base[tid];
    __syncthreads();
    for (int e = tid; e < n; e += 256) {
        g_start[e] = s_start[e];
        int L = s_len[e];
        g_len[e] = L;
        int pos = atomicAdd(&s_base[L], 1);
        g_perm[pos] = e;
    }
}

// ---------------------------------------------------------------------------
__global__ __launch_bounds__(256)
void cast_bf(const float* __restrict__ src, ushort* __restrict__ dst, int n)
{
    int base = (blockIdx.x * 256 + threadIdx.x) * 4;
    if (base < n) {
        float4 v = *(const float4*)(src + base);
        ushort4 o;
        o.x = f2bf(v.x); o.y = f2bf(v.y); o.z = f2bf(v.z); o.w = f2bf(v.w);
        *(ushort4*)(dst + base) = o;
    }
}

// ---------------------------------------------------------------------------
// Transpose + cast ALL weight matrices (float4 reads, verbatim round 16).
// ---------------------------------------------------------------------------
__global__ __launch_bounds__(256)
void transcast_all(const float* __restrict__ Wi, const float* __restrict__ Wh,
                   ushort* __restrict__ WT_all, ushort* __restrict__ WhT_all)
{
    int z = blockIdx.z;
    int l = z >> 1;
    const float* src = ((z & 1) ? Wh : Wi) + (size_t)l * DD * ND3;
    ushort* dst = ((z & 1) ? WhT_all : WT_all) + (size_t)l * ND3 * DD;
    __shared__ float tile[64][65];
    int tid = threadIdx.x;
    int n0 = blockIdx.x * 64, k0 = blockIdx.y * 64;
#pragma unroll
    for (int i = 0; i < 4; ++i) {
        int idx = i * 256 + tid;
        int r = idx >> 4, c4 = idx & 15;
        float4 v = *(const float4*)&src[(size_t)(k0 + r) * ND3 + n0 + c4 * 4];
        tile[r][c4 * 4 + 0] = v.x;
        tile[r][c4 * 4 + 1] = v.y;
        tile[r][c4 * 4 + 2] = v.z;
        tile[r][c4 * 4 + 3] = v.w;
    }
    __syncthreads();
#pragma unroll
    for (int i = 0; i < 4; ++i) {
        int idx = i * 256 + tid;
        int nr = idx >> 4, kq = idx & 15;
        float a0 = tile[kq * 4 + 0][nr];
        float a1 = tile[kq * 4 + 1][nr];
        float a2 = tile[kq * 4 + 2][nr];
        float a3 = tile[kq * 4 + 3][nr];
        ushort4 o;
        o.x = f2bf(a0); o.y = f2bf(a1); o.z = f2bf(a2); o.w = f2bf(a3);
        *(ushort4*)&dst[(size_t)(n0 + nr) * DD + k0 + kq * 4] = o;
    }
}

// ---------------------------------------------------------------------------
// Phase A GEMM (verbatim round 8, verified).
// ---------------------------------------------------------------------------
__global__ __launch_bounds__(256)
void gemm_mfma(const ushort* __restrict__ A, const ushort* __restrict__ BT,
               ushort* __restrict__ C)
{
    __shared__ __align__(16) ushort As[128 * 32];
    __shared__ __align__(16) ushort Bs[128 * 32];
    int tid = threadIdx.x, lane = tid & 63, wv = tid >> 6;
    int m0 = blockIdx.y * 128, n0 = blockIdx.x * 128;
    int wr = wv >> 1, wc = wv & 1;
    f32x4 acc[4][4] = {};

    int ci0 = tid, ci1 = 256 + tid;
    int r0s = ci0 >> 2, r1s = ci1 >> 2;
    int ss0 = (ci0 & 3) ^ ((r0s >> 1) & 3);
    int ss1 = (ci1 & 3) ^ ((r1s >> 1) & 3);
    const ushort* Ar0 = A + (size_t)(m0 + r0s) * DD + ss0 * 8;
    const ushort* Ar1 = A + (size_t)(m0 + r1s) * DD + ss1 * 8;
    const ushort* Br0 = BT + (size_t)(n0 + r0s) * DD + ss0 * 8;
    const ushort* Br1 = BT + (size_t)(n0 + r1s) * DD + ss1 * 8;

    int g = lane >> 4, fr = lane & 15;

    for (int k0 = 0; k0 < DD; k0 += 32) {
        gld_lds16(Ar0 + k0, (char*)As + wv * 1024);
        gld_lds16(Ar1 + k0, (char*)As + 4096 + wv * 1024);
        gld_lds16(Br0 + k0, (char*)Bs + wv * 1024);
        gld_lds16(Br1 + k0, (char*)Bs + 4096 + wv * 1024);
        __syncthreads();

        bf16x8 af[4], bb[4];
#pragma unroll
        for (int mi = 0; mi < 4; ++mi) {
            int row = wr * 64 + mi * 16 + fr;
            int slot = g ^ ((row >> 1) & 3);
            af[mi] = *(const bf16x8*)(As + row * 32 + slot * 8);
        }
#pragma unroll
        for (int ni = 0; ni < 4; ++ni) {
            int row = wc * 64 + ni * 16 + fr;
            int slot = g ^ ((row >> 1) & 3);
            bb[ni] = *(const bf16x8*)(Bs + row * 32 + slot * 8);
        }
#pragma unroll
        for (int mi = 0; mi < 4; ++mi)
#pragma unroll
            for (int ni = 0; ni < 4; ++ni)
                acc[mi][ni] = __builtin_amdgcn_mfma_f32_16x16x32_bf16(
                    af[mi], bb[ni], acc[mi][ni], 0, 0, 0);
        __syncthreads();
    }

    int orow = (lane >> 4) * 4, ocol = lane & 15;
#pragma unroll
    for (int mi = 0; mi < 4; ++mi)
#pragma unroll
        for (int ni = 0; ni < 4; ++ni)
#pragma unroll
            for (int r2 = 0; r2 < 4; ++r2)
                C[(size_t)(m0 + wr * 64 + mi * 16 + orow + r2) * ND3 +
                  n0 + wc * 64 + ni * 16 + ocol] = f2bf(acc[mi][ni][r2]);
}

// ---------------------------------------------------------------------------
// Iteration 0 (verbatim round 8).
// ---------------------------------------------------------------------------
__global__ __launch_bounds__(256)
void it0_kernel(const ushort* __restrict__ xp, const float* __restrict__ Wh,
                const float* __restrict__ bh, const float* __restrict__ h0g,
                const int* __restrict__ term, float* __restrict__ Hnext,
                ushort* __restrict__ Hbfn, ushort* __restrict__ ybf,
                float* __restrict__ yf32, float* __restrict__ finals,
                const int* __restrict__ g_start, const int* __restrict__ g_perm,
                const int* __restrict__ g_nact)
{
    int M = g_nact[0];
    int r = blockIdx.x;
    if (r >= M) return;
    int e = g_perm[r];
    int t = g_start[e];
    int tid = threadIdx.x;
    bool useh0 = (t == 0) && (term[0] == 0);
    __shared__ float h0s[DD];
    __shared__ int s_nz;
    if (tid == 0) s_nz = 0;
    __syncthreads();
    if (useh0) {
        int nz = 0;
#pragma unroll
        for (int j = 0; j < 4; ++j) {
            float v = h0g[tid + j * 256];
            h0s[tid + j * 256] = v;
            nz |= (v != 0.f) ? 1 : 0;
        }
        if (nz) atomicOr(&s_nz, 1);
    }
    __syncthreads();
    bool gemv = useh0 && (s_nz != 0);
#pragma unroll
    for (int j = 0; j < 4; ++j) {
        int c = tid + j * 256;
        float hr = bh[c], hz = bh[DD + c], hn = bh[2 * DD + c];
        if (gemv) {
            for (int k = 0; k < DD; ++k) {
                float hv = h0s[k];
                hr += hv * Wh[(size_t)k * ND3 + c];
                hz += hv * Wh[(size_t)k * ND3 + DD + c];
                hn += hv * Wh[(size_t)k * ND3 + 2 * DD + c];
            }
        }
        float hp = useh0 ? h0s[c] : 0.f;
        float xr = bf2f(xp[(size_t)t * ND3 + c]);
        float xz = bf2f(xp[(size_t)t * ND3 + DD + c]);
        float xn = bf2f(xp[(size_t)t * ND3 + 2 * DD + c]);
        float hnew = gru_out(xr, xz, xn, hr, hz, hn, hp);
        Hnext[(size_t)e * DD + c] = hnew;
        Hbfn[(size_t)e * DD + c] = f2bf(hnew);
        if (yf32) yf32[(size_t)t * DD + c] = hnew;
        else      ybf[(size_t)t * DD + c] = f2bf(hnew);
        if (t == TT - 1) finals[c] = hnew;
    }
}

// ---------------------------------------------------------------------------
// Phase B fused (verbatim round 17 — verified best: 512 thr / 8 waves,
// per-rg per-producer flag slots on private 64B lines, depth-2
// counted-vmcnt B pipeline, flag-independent prefetch, bias hoist).
// ---------------------------------------------------------------------------
__global__ __launch_bounds__(512)
void phaseb_kernel(float* __restrict__ Hb0, float* __restrict__ Hb1,
                   ushort* __restrict__ Hbf0, ushort* __restrict__ Hbf1,
                   const ushort* __restrict__ xp, const ushort* __restrict__ WhT,
                   const float* __restrict__ bh, ushort* __restrict__ ybf,
                   float* __restrict__ yf32, float* __restrict__ finals,
                   const int* __restrict__ g_start, const int* __restrict__ g_perm,
                   const int* __restrict__ g_nact, unsigned* __restrict__ flags)
{
    __shared__ __align__(16) ushort As[3 * 32 * 64];     // 3 x 4 KB
    __shared__ __align__(16) ushort Bs[3 * 192 * 64];    // 3 x 24 KB
    __shared__ int s_e[32], s_t[32], s_v[32];
    int tid = threadIdx.x, lane = tid & 63, wv = tid >> 6;
    int fr = lane & 15, g = lane >> 4;
    int rw = (wv & 1) * 16, hw = (wv >> 1) * 16;
    int cs = blockIdx.x & 15, bw = blockIdx.x >> 4;
    int c0 = cs * 64;
    int col = c0 + hw + fr;
    float bhv0 = bh[col], bhv1 = bh[DD + col], bhv2 = bh[2 * DD + col];

    // B staging sources (pre-swizzled global) — constant per block
    const ushort* srcB[3];
#pragma unroll
    for (int p = 0; p < 3; ++p) {
        int c = p * 512 + tid;
        int j = c >> 3;
        int f = j >> 6;
        int coln = c0 + (j & 63);
        int sl = (c & 7) ^ (j & 7);
        srcB[p] = WhT + (size_t)(f * DD + coln) * DD + sl * 8;
    }

    for (int it = 1; it < MAXIT; ++it) {
        int M = g_nact[it];   // uniform, read-only
        if (bw * 32 >= M) break;   // monotone: never active again
        float*  Hp   = (it & 1) ? Hb0 : Hb1;
        float*  Hn   = (it & 1) ? Hb1 : Hb0;
        ushort* Hbfp = (it & 1) ? Hbf0 : Hbf1;
        ushort* Hbfn = (it & 1) ? Hbf1 : Hbf0;

        for (int rg = bw; rg * 32 < M; rg += 16) {
            int r0 = rg * 32;

            __syncthreads();   // LDS reuse guard (prev tile fully read)
            if (tid < 32) {
                int r = r0 + tid;
                int v = (r < M) ? 1 : 0;
                int e = v ? g_perm[r] : 0;
                s_e[tid] = e;
                s_v[tid] = v;
                s_t[tid] = v ? (g_start[e] + it) : 0;
            }
            __syncthreads();   // publish s_e/s_t/s_v

            // --- flag-independent prefetch (runs while we wait) ---
            gld_lds16(srcB[0], (char*)Bs + wv * 1024);
            gld_lds16(srcB[1], (char*)Bs + 8192 + wv * 1024);
            gld_lds16(srcB[2], (char*)Bs + 16384 + wv * 1024);
            gld_lds16(srcB[0] + 64, (char*)Bs + 24576 + wv * 1024);
            gld_lds16(srcB[1] + 64, (char*)Bs + 24576 + 8192 + wv * 1024);
            gld_lds16(srcB[2] + 64, (char*)Bs + 24576 + 16384 + wv * 1024);
            float xrv[4], xzv[4], xnv[4];
#pragma unroll
            for (int r2 = 0; r2 < 4; ++r2) {
                int row = rw + g * 4 + r2;
                size_t tb = (size_t)s_t[row] * ND3;
                xrv[r2] = bf2f(xp[tb + col]);
                xzv[r2] = bf2f(xp[tb + DD + col]);
                xnv[r2] = bf2f(xp[tb + 2 * DD + col]);
            }

            // --- wait for the 16 it-1 producers (parallel per-slot poll) ---
            if (it > 1 && tid < 16) {
                const unsigned* slot =
                    flags + ((size_t)(it - 1) * NRG + rg) * 256 + tid * 16;
                while (__hip_atomic_load(slot, __ATOMIC_RELAXED,
                                         __HIP_MEMORY_SCOPE_AGENT) == 0u)
                    __builtin_amdgcn_s_sleep(1);
            }
            __syncthreads();

            // --- flag-dependent: A-strip + Hp (LLC-coherent) ---
            int arowi = tid >> 4;
            int rr = r0 + arowi; if (rr > M - 1) rr = M - 1;
            int eA = g_perm[rr];
            int s8 = tid & 15;
            const ull_t* srcA8 = (const ull_t*)(Hbfp + (size_t)eA * DD) + s8;
            ull_t areg[16];
#pragma unroll
            for (int kk = 0; kk < 16; ++kk)
                areg[kk] = __hip_atomic_load(srcA8 + kk * 16, __ATOMIC_RELAXED,
                                             __HIP_MEMORY_SCOPE_AGENT);
            float hpv[4];
#pragma unroll
            for (int r2 = 0; r2 < 4; ++r2) {
                int row = rw + g * 4 + r2;
                hpv[r2] = __hip_atomic_load(Hp + (size_t)s_e[row] * DD + col,
                                            __ATOMIC_RELAXED, __HIP_MEMORY_SCOPE_AGENT);
            }
            int dstb = arowi * 128 + ((((s8 >> 1) ^ (arowi & 7)) << 1) | (s8 & 1)) * 8;
            asm volatile("s_waitcnt vmcnt(0)" ::: "memory");
            *(ull_t*)((char*)As + dstb) = areg[0];
            *(ull_t*)((char*)As + 4096 + dstb) = areg[1];

            f32x4 acc[3] = {};
            int arow = rw + fr;
#pragma unroll
            for (int kk = 0; kk < 16; ++kk) {
                if (kk == 15)
                    asm volatile("s_waitcnt vmcnt(0) lgkmcnt(0)" ::: "memory");
                else
                    asm volatile("s_waitcnt vmcnt(3) lgkmcnt(0)" ::: "memory");
                __builtin_amdgcn_s_barrier();
                if (kk < 14) {
                    const int nb = (kk + 2) % 3;
                    char* bdst = (char*)Bs + nb * 24576;
                    gld_lds16(srcB[0] + (kk + 2) * 64, bdst + wv * 1024);
                    gld_lds16(srcB[1] + (kk + 2) * 64, bdst + 8192 + wv * 1024);
                    gld_lds16(srcB[2] + (kk + 2) * 64, bdst + 16384 + wv * 1024);
                    *(ull_t*)((char*)As + nb * 4096 + dstb) = areg[kk + 2];
                }
                const int cb = kk % 3;
                const ushort* Acur = As + cb * 2048;
                const ushort* Bcur = Bs + cb * 12288;
#pragma unroll
                for (int kw = 0; kw < 2; ++kw) {
                    int sA = (kw * 4 + g) ^ (arow & 7);
                    bf16x8 af = *(const bf16x8*)(Acur + arow * 64 + sA * 8);
#pragma unroll
                    for (int f = 0; f < 3; ++f) {
                        int jf = f * 64 + hw + fr;
                        int sB = (kw * 4 + g) ^ (jf & 7);
                        bf16x8 bbv = *(const bf16x8*)(Bcur + jf * 64 + sB * 8);
                        acc[f] = __builtin_amdgcn_mfma_f32_16x16x32_bf16(af, bbv, acc[f], 0, 0, 0);
                    }
                }
            }

#pragma unroll
            for (int r2 = 0; r2 < 4; ++r2) {
                int row = rw + g * 4 + r2;
                if (!s_v[row]) continue;   // uniform across the fr^1 pair
                int e = s_e[row], t = s_t[row];
                float hr = acc[0][r2] + bhv0;
                float hz = acc[1][r2] + bhv1;
                float hn = acc[2][r2] + bhv2;
                float hnew = gru_out(xrv[r2], xzv[r2], xnv[r2], hr, hz, hn, hpv[r2]);
                __hip_atomic_store(Hn + (size_t)e * DD + col, hnew,
                                   __ATOMIC_RELAXED, __HIP_MEMORY_SCOPE_AGENT);
                ushort mybf = f2bf(hnew);
                unsigned other = __shfl_xor((unsigned)mybf, 1);
                if ((fr & 1) == 0)
                    __hip_atomic_store((unsigned*)(Hbfn + (size_t)e * DD + col),
                                       (unsigned)mybf | (other << 16),
                                       __ATOMIC_RELAXED, __HIP_MEMORY_SCOPE_AGENT);
                if (yf32) yf32[(size_t)t * DD + col] = hnew;
                else      ybf[(size_t)t * DD + col] = mybf;
                if (t == TT - 1) finals[col] = hnew;
            }

            __syncthreads();   // drain epilogue stores (vmcnt(0)) before flag
            if (tid == 0)
                __hip_atomic_store(
                    flags + ((size_t)it * NRG + rg) * 256 + cs * 16, 1u,
                    __ATOMIC_RELAXED, __HIP_MEMORY_SCOPE_AGENT);
        }
    }
}

// ---------------------------------------------------------------------------
// Cleanup (verbatim round 8; no-op when no episode exceeds MAXIT).
// ---------------------------------------------------------------------------
__global__ __launch_bounds__(256)
void cleanup_kernel(const float* __restrict__ Hlast, const ushort* __restrict__ xp,
                    const float* __restrict__ Wh, const float* __restrict__ bh,
                    ushort* __restrict__ ybf, float* __restrict__ yf32,
                    float* __restrict__ finals, const int* __restrict__ g_start,
                    const int* __restrict__ g_len, const int* __restrict__ g_perm,
                    const int* __restrict__ g_nact)
{
    int Mt = g_nact[MAXIT];
    if (Mt == 0) return;
    __shared__ float h[DD];
    int tid = threadIdx.x;
    for (int r = blockIdx.x; r < Mt; r += gridDim.x) {
        int e = g_perm[r];
        int s0 = g_start[e];
        int L = g_len[e];
#pragma unroll
        for (int j = 0; j < 4; ++j) h[tid + j * 256] = Hlast[(size_t)e * DD + tid + j * 256];
        __syncthreads();
        for (int i = MAXIT; i < L; ++i) {
            int t = s0 + i;
            float hnew[4];
#pragma unroll
            for (int j = 0; j < 4; ++j) {
                int c = tid + j * 256;
                float hr = bh[c], hz = bh[DD + c], hn = bh[2 * DD + c];
                for (int k = 0; k < DD; ++k) {
                    float hv = h[k];
                    hr += hv * Wh[(size_t)k * ND3 + c];
                    hz += hv * Wh[(size_t)k * ND3 + DD + c];
                    hn += hv * Wh[(size_t)k * ND3 + 2 * DD + c];
                }
                float xr = bf2f(xp[(size_t)t * ND3 + c]);
                float xz = bf2f(xp[(size_t)t * ND3 + DD + c]);
                float xn = bf2f(xp[(size_t)t * ND3 + 2 * DD + c]);
                float hp = h[c];
                hnew[j] = gru_out(xr, xz, xn, hr, hz, hn, hp);
                if (yf32) yf32[(size_t)t * DD + c] = hnew[j];
                else      ybf[(size_t)t * DD + c] = f2bf(hnew[j]);
                if (t == TT - 1) finals[c] = hnew[j];
            }
            __syncthreads();
#pragma unroll
            for (int j = 0; j < 4; ++j) h[tid + j * 256] = hnew[j];
            __syncthreads();
        }
        __syncthreads();
    }
}

// ---------------------------------------------------------------------------
extern "C" void kernel_launch(void* const* d_in, const int* in_sizes, int n_in,
                              void* d_out, int out_size, void* d_ws, size_t ws_size,
                              hipStream_t stream)
{
    const float* x_in = (const float*)d_in[0];
    const int*   term = (const int*)d_in[1];
    const float* h0   = (const float*)d_in[2];
    const float* Wi   = (const float*)d_in[3];
    const float* Wh   = (const float*)d_in[4];
    const float* bh   = (const float*)d_in[5];
    float* out = (float*)d_out;

    ushort* xp      = (ushort*)d_ws;                      // TT*ND3 bf16
    float*  Hb0     = (float*)(xp + (size_t)TT * ND3);    // TT*DD fp32
    float*  Hb1     = Hb0 + (size_t)TT * DD;              // TT*DD fp32
    ushort* Hbf0    = (ushort*)(Hb1 + (size_t)TT * DD);   // TT*DD bf16
    ushort* Hbf1    = Hbf0 + (size_t)TT * DD;             // TT*DD bf16
    ushort* Xbf     = Hbf1 + (size_t)TT * DD;             // TT*DD bf16
    ushort* Yb0     = Xbf + (size_t)TT * DD;              // TT*DD bf16
    ushort* Yb1     = Yb0 + (size_t)TT * DD;              // TT*DD bf16
    ushort* WT_all  = Yb1 + (size_t)TT * DD;              // LL*ND3*DD bf16
    ushort* WhT_all = WT_all + (size_t)LL * ND3 * DD;     // LL*ND3*DD bf16
    int* ib      = (int*)(WhT_all + (size_t)LL * ND3 * DD);
    int* g_start = ib;                 // TT
    int* g_len   = ib + TT;            // TT
    int* g_perm  = ib + 2 * TT;        // TT
    int* g_nact  = ib + 3 * TT;        // 64
    unsigned* flagws = (unsigned*)(ib + 3 * TT + 64);   // LL*MAXIT*NRG*16*16 uints

    hipMemsetAsync(flagws, 0,
                   (size_t)LL * MAXIT * NRG * 16 * 16 * sizeof(unsigned), stream);
    seg_kernel<<<1, 256, 0, stream>>>(term, g_start, g_len, g_perm, g_nact);
    cast_bf<<<(TT * DD / 4 + 255) / 256, 256, 0, stream>>>(x_in, Xbf, TT * DD);
    transcast_all<<<dim3(ND3 / 64, DD / 64, 2 * LL), 256, 0, stream>>>(
        Wi, Wh, WT_all, WhT_all);

    const ushort* Abf[4] = { Xbf, Yb0, Yb1, Yb0 };
    ushort*       Ybo[4] = { Yb0, Yb1, Yb0, nullptr };

    for (int l = 0; l < LL; ++l) {
        const float* Whl = Wh + (size_t)l * DD * ND3;
        const float* bhl = bh + (size_t)l * ND3;
        const ushort* WTl  = WT_all + (size_t)l * ND3 * DD;
        const ushort* WhTl = WhT_all + (size_t)l * ND3 * DD;
        float* yf32 = (l == LL - 1) ? out : nullptr;
        ushort* ybf = Ybo[l];
        float* finals = out + (size_t)TT * DD + (size_t)l * DD;

        gemm_mfma<<<dim3(ND3 / 128, TT / 128), 256, 0, stream>>>(Abf[l], WTl, xp);

        it0_kernel<<<TT, 256, 0, stream>>>(xp, Whl, bhl, h0 + (size_t)l * DD, term,
                                           Hb0, Hbf0, ybf, yf32, finals,
                                           g_start, g_perm, g_nact);

        phaseb_kernel<<<NBLK, 512, 0, stream>>>(
            Hb0, Hb1, Hbf0, Hbf1, xp, WhTl, bhl, ybf, yf32, finals,
            g_start, g_perm, g_nact,
            flagws + (size_t)l * MAXIT * NRG * 256);

        float* Hlast = ((MAXIT - 1) & 1) ? Hb1 : Hb0;
        cleanup_kernel<<<64, 256, 0, stream>>>(Hlast, xp, Whl, bhl, ybf, yf32,
                                               finals, g_start, g_len, g_perm,
                                               g_nact);
    }
}